// Round 11
// baseline (370.720 us; speedup 1.0000x reference)
//
#include <hip/hip_runtime.h>
#include <stdint.h>

#define T_LEN 1024
#define MEM_LEN 1024
#define C_LEN 2048
#define B_SZ 4
#define DM_ 1024
#define NH 16
#define HD 64

typedef __attribute__((ext_vector_type(8))) short short8;
typedef __attribute__((ext_vector_type(4))) float f32x4;
typedef __attribute__((ext_vector_type(4))) unsigned short ushort4v;
typedef __attribute__((ext_vector_type(4))) float float4v;

__device__ __forceinline__ unsigned short f2bf(float f) {
  union { float f; unsigned int u; } v; v.f = f;
  unsigned int r = v.u + 0x7fffu + ((v.u >> 16) & 1u);
  return (unsigned short)(r >> 16);
}
__device__ __forceinline__ float bf2f(unsigned short b) {
  union { unsigned int u; float f; } v; v.u = ((unsigned int)b) << 16;
  return v.f;
}
__device__ __forceinline__ f32x4 mfma16(short8 a, short8 b, f32x4 c) {
  return __builtin_amdgcn_mfma_f32_16x16x32_bf16(a, b, c, 0, 0, 0);
}

// ---------------- converts ----------------
__global__ void k_cat_convert(const float* __restrict__ m, const float* __restrict__ h,
                              unsigned short* __restrict__ outB) {
  int idx = blockIdx.x * 256 + threadIdx.x;
  const int MQ = (MEM_LEN * B_SZ * DM_) / 4;
  float4v v;
  if (idx < MQ) v = ((const float4v*)m)[idx];
  else          v = ((const float4v*)h)[idx - MQ];
  ushort4v o;
  o.x = f2bf(v.x); o.y = f2bf(v.y); o.z = f2bf(v.z); o.w = f2bf(v.w);
  ((ushort4v*)outB)[idx] = o;
}

__global__ void k_f32_to_bf16(const float* __restrict__ in, unsigned short* __restrict__ outB, int nq) {
  int idx = blockIdx.x * 256 + threadIdx.x;
  if (idx >= nq) return;
  float4v v = ((const float4v*)in)[idx];
  ushort4v o;
  o.x = f2bf(v.x); o.y = f2bf(v.y); o.z = f2bf(v.z); o.w = f2bf(v.w);
  ((ushort4v*)outB)[idx] = o;
}

// transpose f32 [R][Ccols] -> bf16 [Ccols][R]
__global__ void k_transpose_bf16(const float* __restrict__ in, unsigned short* __restrict__ out,
                                 int R, int Ccols) {
  __shared__ float tile[32][33];
  int c0 = blockIdx.x * 32, r0 = blockIdx.y * 32;
  int tx = threadIdx.x & 31, ty = threadIdx.x >> 5;
#pragma unroll
  for (int p = 0; p < 4; ++p)
    tile[ty + 8 * p][tx] = in[(size_t)(r0 + ty + 8 * p) * Ccols + c0 + tx];
  __syncthreads();
#pragma unroll
  for (int p = 0; p < 4; ++p)
    out[(size_t)(c0 + ty + 8 * p) * R + r0 + tx] = f2bf(tile[tx][ty + 8 * p]);
}

// ---------------- GEMM: C[M][col0 + N] = A[M][K] * BT[N][K]^T, XCD-swizzled grid ----------------
template <int EPI>
__global__ __launch_bounds__(256) void k_gemm(const unsigned short* __restrict__ A,
                                              const unsigned short* __restrict__ BT,
                                              void* __restrict__ Cout, int M, int N, int K,
                                              int ldc, int col0) {
  __shared__ unsigned short As[128 * 64];
  __shared__ unsigned short Bs[128 * 64];
  const int tid = threadIdx.x;
  const int w = tid >> 6, l = tid & 63;
  const int wm = w >> 1, wn = w & 1;
  const int lg = l >> 4, lr = l & 15;
  const int gx = gridDim.x;
  const int pid = blockIdx.y * gx + blockIdx.x;
  const int xcd = pid & 7;
  const int idx = pid >> 3;
  const int cb = idx % gx;
  const int rb = (idx / gx) * 8 + xcd;
  const int m0 = rb * 128, n0 = cb * 128;
  f32x4 acc[4][4] = {};
  const int lrow8 = l >> 3;
  const int scol = (l & 7) * 8;
  const unsigned short* Abase = A + (size_t)m0 * K;
  const unsigned short* Bbase = BT + (size_t)n0 * K;
  for (int kt = 0; kt < K; kt += 64) {
    __syncthreads();
#pragma unroll
    for (int q = 0; q < 4; ++q) {
      int chunk = w * 4 + q;
      int row = chunk * 8 + lrow8;
      __builtin_amdgcn_global_load_lds(
          (const __attribute__((address_space(1))) void*)(Abase + (size_t)row * K + kt + scol),
          (__attribute__((address_space(3))) void*)(As + chunk * 512), 16, 0, 0);
      __builtin_amdgcn_global_load_lds(
          (const __attribute__((address_space(1))) void*)(Bbase + (size_t)row * K + kt + scol),
          (__attribute__((address_space(3))) void*)(Bs + chunk * 512), 16, 0, 0);
    }
    __syncthreads();
#pragma unroll
    for (int ks = 0; ks < 2; ++ks) {
      short8 a[4], bb[4];
#pragma unroll
      for (int mi = 0; mi < 4; ++mi)
        a[mi] = *(const short8*)&As[(wm * 64 + mi * 16 + lr) * 64 + ks * 32 + lg * 8];
#pragma unroll
      for (int ni = 0; ni < 4; ++ni)
        bb[ni] = *(const short8*)&Bs[(wn * 64 + ni * 16 + lr) * 64 + ks * 32 + lg * 8];
#pragma unroll
      for (int mi = 0; mi < 4; ++mi)
#pragma unroll
        for (int ni = 0; ni < 4; ++ni)
          acc[mi][ni] = mfma16(a[mi], bb[ni], acc[mi][ni]);
    }
  }
#pragma unroll
  for (int mi = 0; mi < 4; ++mi)
#pragma unroll
    for (int ni = 0; ni < 4; ++ni)
#pragma unroll
      for (int r = 0; r < 4; ++r) {
        int row = m0 + wm * 64 + mi * 16 + lg * 4 + r;
        int col = col0 + n0 + wn * 64 + ni * 16 + lr;
        if (EPI == 0)
          ((unsigned short*)Cout)[(size_t)row * ldc + col] = f2bf(acc[mi][ni][r]);
        else
          ((float*)Cout)[(size_t)row * ldc + col] = acc[mi][ni][r];
      }
}

// ---------------- V transpose: wheads v-part -> VT[b][n][d][c] ----------------
__global__ void k_vt(const unsigned short* __restrict__ wheads, unsigned short* __restrict__ VT) {
  __shared__ unsigned short tile[64][72];
  int c0 = blockIdx.x * 64;
  int n = blockIdx.y, b = blockIdx.z;
  int t = threadIdx.x;
#pragma unroll
  for (int p = 0; p < 16; ++p) {
    int idx = p * 256 + t;
    int r = idx >> 6, d = idx & 63;
    tile[d][r] = wheads[(size_t)((c0 + r) * 4 + b) * 3072 + 2048 + n * 64 + d];
  }
  __syncthreads();
#pragma unroll
  for (int p = 0; p < 16; ++p) {
    int idx = p * 256 + t;
    int d = idx >> 6, c = idx & 63;
    VT[(size_t)((b * 16 + n) * 64 + d) * 2048 + c0 + c] = tile[d][c];
  }
}

// ---------------- repack: wheads -> Kp[b][n][c][d], Qp[b][n][t][d]; RkG -> Rkp[n][c][d] ----
__global__ void k_repack(const unsigned short* __restrict__ wheads,
                         const unsigned short* __restrict__ RkG,
                         unsigned short* __restrict__ Kp,
                         unsigned short* __restrict__ Qp,
                         unsigned short* __restrict__ Rkp) {
  int gid = blockIdx.x * 256 + threadIdx.x;
  const int NK = (B_SZ * NH * C_LEN * HD) / 8;   // 1048576
  const int NQ = (B_SZ * NH * T_LEN * HD) / 8;   // 524288
  if (gid < NK) {
    int d0 = (gid & 7) * 8;
    int c  = (gid >> 3) & 2047;
    int n  = (gid >> 14) & 15;
    int b  = gid >> 18;
    short8 v = *(const short8*)&wheads[(size_t)(c * 4 + b) * 3072 + 1024 + n * 64 + d0];
    *(short8*)&Kp[(size_t)gid * 8] = v;
  } else if (gid < NK + NQ) {
    int g2 = gid - NK;
    int d0 = (g2 & 7) * 8;
    int t  = (g2 >> 3) & 1023;
    int n  = (g2 >> 13) & 15;
    int b  = g2 >> 17;
    short8 v = *(const short8*)&wheads[(size_t)((MEM_LEN + t) * 4 + b) * 3072 + n * 64 + d0];
    *(short8*)&Qp[(size_t)g2 * 8] = v;
  } else {
    int g3 = gid - NK - NQ;
    int d0 = (g3 & 7) * 8;
    int c  = (g3 >> 3) & 2047;
    int n  = g3 >> 14;
    short8 v = *(const short8*)&RkG[(size_t)c * 1024 + n * 64 + d0];
    *(short8*)&Rkp[(size_t)g3 * 8] = v;
  }
}

// ---------------- bias dot scalars ----------------
__global__ void k_bias_dots(const unsigned short* __restrict__ Kp,
                            const unsigned short* __restrict__ Rkp,
                            const float* __restrict__ rwb, const float* __restrict__ rrb,
                            float* __restrict__ uk, float* __restrict__ vr) {
  int gid = blockIdx.x * 256 + threadIdx.x;
  if (gid < B_SZ * NH * C_LEN) {
    int bn = gid >> 11;
    int n = bn & 15;
    const unsigned short* kp = Kp + (size_t)gid * 64;
    float s = 0.f;
#pragma unroll
    for (int q = 0; q < 8; ++q) {
      short8 v = *(const short8*)&kp[q * 8];
#pragma unroll
      for (int e = 0; e < 8; ++e)
        s += bf2f((unsigned short)v[e]) * rwb[n * 64 + q * 8 + e];
    }
    uk[gid] = s;
  } else {
    int g2 = gid - B_SZ * NH * C_LEN;
    int n = g2 >> 11;
    const unsigned short* rp = Rkp + (size_t)g2 * 64;
    float s = 0.f;
#pragma unroll
    for (int q = 0; q < 8; ++q) {
      short8 v = *(const short8*)&rp[q * 8];
#pragma unroll
      for (int e = 0; e < 8; ++e)
        s += bf2f((unsigned short)v[e]) * rrb[n * 64 + q * 8 + e];
    }
    vr[g2] = s;
  }
}

// ---------------- split-j flash attention, KVBLK=32 ----------------
// Halved tile: K 32x64, V 64x32, P 16x32 -> LDS ~21 KB -> 6-7 blocks/CU cap
// (R10 was 42 KB -> 3 cap, 28% measured). More independent block-streams per
// CU hide band/P/barrier latency. Same rel-shift math (gb[0..2], x<=46<48).
__device__ __forceinline__ void stage_tile(const unsigned short* __restrict__ Kbase,
                                           const unsigned short* __restrict__ Vbase,
                                           unsigned short* ksBuf, unsigned short* vsBuf,
                                           int j0, int tid) {
  {
    int row = tid >> 3;            // 0..31
    int slot = tid & 7;
    int ss = slot ^ (row & 7);     // source pre-swizzle (rule #21)
    __builtin_amdgcn_global_load_lds(
        (const __attribute__((address_space(1))) void*)(Kbase + (size_t)(j0 + row) * 64 + ss * 8),
        (__attribute__((address_space(3))) void*)(ksBuf + tid * 8), 16, 0, 0);
  }
  {
    int d = tid >> 2;              // 0..63
    int slot = tid & 3;
    int ss = slot ^ (d & 3);
    __builtin_amdgcn_global_load_lds(
        (const __attribute__((address_space(1))) void*)(Vbase + (size_t)d * 2048 + j0 + ss * 8),
        (__attribute__((address_space(3))) void*)(vsBuf + tid * 8), 16, 0, 0);
  }
}

__global__ __launch_bounds__(256) void k_attn(const unsigned short* __restrict__ Qp,
                                              const unsigned short* __restrict__ Kp,
                                              const unsigned short* __restrict__ VT,
                                              const unsigned short* __restrict__ Rkp,
                                              const float* __restrict__ uk,
                                              const float* __restrict__ vr,
                                              float* __restrict__ po,
                                              float* __restrict__ psumG) {
  __shared__ __align__(16) unsigned short Ks[2][32 * 64];
  __shared__ __align__(16) unsigned short Vs[2][64 * 32];
  __shared__ unsigned short P[4][16][36];
  const int tid = threadIdx.x;
  const int w = tid >> 6, l = tid & 63;
  const int lg = l >> 4, lr = l & 15;
  // XCD-locality: all 48 (xt,s) blocks of one bn land on one XCD (L%8 const)
  const int L = blockIdx.x;
  const int bnlo = L & 7;
  const int rest = L >> 3;          // 0..383
  const int bnhi = rest / 48;
  const int inner = rest - bnhi * 48;  // 0..47
  const int xt = inner / 3;
  const int s  = inner - xt * 3;
  const int bn = bnhi * 8 + bnlo;
  const int i0 = xt * 64;
  const int n = bn & 15, b = bn >> 4;
  const int wrow = i0 + w * 16;

  const int nt32 = 2 * (xt + 17);         // 32-wide tiles
  const int t0 = (s * nt32) / 3;
  const int t1 = ((s + 1) * nt32) / 3;    // chunk length 11..22

  const unsigned short* Kbase = Kp + (size_t)bn * 2048 * 64;
  const unsigned short* Vbase = VT + (size_t)bn * 64 * 2048;
  const unsigned short* Rkbase = Rkp + (size_t)n * 2048 * 64;

  short8 aq0, aq1;
  {
    const unsigned short* qp = Qp + (size_t)(bn * 1024 + wrow + lr) * 64 + lg * 8;
    aq0 = *(const short8*)qp;
    aq1 = *(const short8*)(qp + 32);
  }
  float psum[4];
  f32x4 o[4];
#pragma unroll
  for (int r = 0; r < 4; ++r) psum[r] = 0.f;
#pragma unroll
  for (int df = 0; df < 4; ++df) o[df] = (f32x4){0.f, 0.f, 0.f, 0.f};

  const float* ukp = uk + (size_t)bn * 2048;
  const float* vrp = vr + (size_t)n * 2048;

  // prologue: stage tiles t0, t0+1 (4 loads/thread outstanding)
  stage_tile(Kbase, Vbase, Ks[0], Vs[0], t0 * 32, tid);
  stage_tile(Kbase, Vbase, Ks[1], Vs[1], (t0 + 1) * 32, tid);

  const float EXPC = 0.18033688011112042f;  // 0.125 * log2(e)

  for (int jt = t0; jt < t1; ++jt) {
    const int j0 = jt * 32;
    const int cur = (jt - t0) & 1;
    if (jt + 1 < t1) { asm volatile("s_waitcnt vmcnt(2)" ::: "memory"); }
    else             { asm volatile("s_waitcnt vmcnt(0)" ::: "memory"); }
    __builtin_amdgcn_s_barrier();

    f32x4 sac[2];
#pragma unroll
    for (int jf = 0; jf < 2; ++jf) sac[jf] = (f32x4){0.f, 0.f, 0.f, 0.f};
    // AC = q . k  (from swizzled LDS)
#pragma unroll
    for (int jf = 0; jf < 2; ++jf) {
      int row = jf * 16 + lr;
      int rx = row & 7;
      short8 k0 = *(const short8*)&Ks[cur][row * 64 + ((lg ^ rx) * 8)];
      short8 k1 = *(const short8*)&Ks[cur][row * 64 + (((4 + lg) ^ rx) * 8)];
      sac[jf] = mfma16(aq0, k0, sac[jf]);
      sac[jf] = mfma16(aq1, k1, sac[jf]);
    }
    // BD band fragments (48 rows cover x = jf*16+delta <= 46)
    const int kbw = j0 + 1008 - i0 - w * 16;
    f32x4 gb[3];
#pragma unroll
    for (int jg = 0; jg < 3; ++jg) {
      int rowK = kbw + jg * 16 + lr;
      short8 b0 = {}, b1 = {};
      float vrv = 0.f;
      if (rowK < C_LEN) {
        const unsigned short* rp = Rkbase + (size_t)rowK * 64 + lg * 8;
        b0 = *(const short8*)rp;
        b1 = *(const short8*)(rp + 32);
        vrv = vrp[rowK];
      }
      f32x4 g = (f32x4){0.f, 0.f, 0.f, 0.f};
      g = mfma16(aq0, b0, g);
      g = mfma16(aq1, b1, g);
#pragma unroll
      for (int r = 0; r < 4; ++r) g[r] += vrv;
      gb[jg] = g;
    }
    float ukv[2];
#pragma unroll
    for (int jf = 0; jf < 2; ++jf) ukv[jf] = ukp[j0 + jf * 16 + lr];
    // shuffle-gather the diagonal band; p = exp2(score*C) directly (no max)
    float p[2][4];
#pragma unroll
    for (int r = 0; r < 4; ++r) {
      const int R = lg * 4 + r;
      const int delta = lr + 15 - R;
      const int src = (l & 48) | (delta & 15);
      float v0 = __shfl(gb[0][r], src);
      float v1 = __shfl(gb[1][r], src);
      float v2 = __shfl(gb[2][r], src);
      const bool hi = delta >= 16;
      float bd0 = hi ? v1 : v0;
      float bd1 = hi ? v2 : v1;
      const int jlim = i0 + w * 16 + R + MEM_LEN;
      int j = j0 + lr;
      p[0][r] = (j > jlim) ? 0.f : exp2f((sac[0][r] + bd0 + ukv[0]) * EXPC);
      j += 16;
      p[1][r] = (j > jlim) ? 0.f : exp2f((sac[1][r] + bd1 + ukv[1]) * EXPC);
    }
#pragma unroll
    for (int jf = 0; jf < 2; ++jf)
#pragma unroll
      for (int r = 0; r < 4; ++r) psum[r] += p[jf][r];
#pragma unroll
    for (int jf = 0; jf < 2; ++jf)
#pragma unroll
      for (int r = 0; r < 4; ++r)
        P[w][lg * 4 + r][jf * 16 + lr] = f2bf(p[jf][r]);
    // PV (V from swizzled LDS), one k-slice of 32
    {
      short8 ap = *(const short8*)&P[w][lr][lg * 8];
#pragma unroll
      for (int df = 0; df < 4; ++df) {
        int row = df * 16 + lr;
        short8 vv = *(const short8*)&Vs[cur][row * 32 + ((lg ^ (row & 3)) * 8)];
        o[df] = mfma16(ap, vv, o[df]);
      }
    }
    __builtin_amdgcn_s_barrier();
    if (jt + 2 < t1)
      stage_tile(Kbase, Vbase, Ks[cur], Vs[cur], (jt + 2) * 32, tid);
  }
  // write partials
  const int pbase = (bn * 16 + xt) * 3 + s;
  float* poB = po + (size_t)pbase * 4096;
#pragma unroll
  for (int r = 0; r < 4; ++r) {
    float v = psum[r];
    v += __shfl_xor(v, 1);
    v += __shfl_xor(v, 2);
    v += __shfl_xor(v, 4);
    v += __shfl_xor(v, 8);
    if (lr == 0) psumG[pbase * 64 + w * 16 + lg * 4 + r] = v;
  }
#pragma unroll
  for (int df = 0; df < 4; ++df)
#pragma unroll
    for (int r = 0; r < 4; ++r)
      poB[(w * 16 + lg * 4 + r) * 64 + df * 16 + lr] = o[df][r];
}

// combine split partials, normalize, emit bf16 vec[t][b][n*64+d]
__global__ __launch_bounds__(256) void k_ared(const float* __restrict__ po,
                                              const float* __restrict__ psumG,
                                              unsigned short* __restrict__ vec) {
  const int idx = blockIdx.x;      // bn*16 + xt
  const int tid = threadIdx.x;
  const int bn = idx >> 4, xt = idx & 15;
  const int b = bn >> 4, n = bn & 15;
  __shared__ float rs[64];
  if (tid < 64) {
    const float* q = psumG + idx * 192;
    rs[tid] = q[tid] + q[tid + 64] + q[tid + 128];
  }
  __syncthreads();
  const float4v* p0 = (const float4v*)(po + (size_t)(idx * 3 + 0) * 4096);
  const float4v* p1 = (const float4v*)(po + (size_t)(idx * 3 + 1) * 4096);
  const float4v* p2 = (const float4v*)(po + (size_t)(idx * 3 + 2) * 4096);
#pragma unroll
  for (int k = 0; k < 4; ++k) {
    int e = tid + k * 256;          // float4 index 0..1023
    int row = e >> 4, d4 = e & 15;
    float4v a = p0[e], bb = p1[e], c = p2[e];
    float inv = 1.f / rs[row];
    int t = xt * 64 + row;
    ushort4v ov;
    ov.x = f2bf((a.x + bb.x + c.x) * inv);
    ov.y = f2bf((a.y + bb.y + c.y) * inv);
    ov.z = f2bf((a.z + bb.z + c.z) * inv);
    ov.w = f2bf((a.w + bb.w + c.w) * inv);
    *(ushort4v*)&vec[(size_t)(t * 4 + b) * 1024 + n * 64 + d4 * 4] = ov;
  }
}

// ---------------- residual + layernorm ----------------
__global__ __launch_bounds__(256) void k_ln(const float* __restrict__ xg, const float* __restrict__ h,
                                            const float* __restrict__ gamma, const float* __restrict__ beta,
                                            float* __restrict__ out) {
  const int row = blockIdx.x;
  const int t = threadIdx.x;
  __shared__ float red1[4], red2[4];
  float4v xv = ((const float4v*)(xg + (size_t)row * 1024))[t];
  float4v hv = ((const float4v*)(h + (size_t)row * 1024))[t];
  float x0 = xv.x + hv.x, x1 = xv.y + hv.y, x2 = xv.z + hv.z, x3 = xv.w + hv.w;
  float s = x0 + x1 + x2 + x3;
#pragma unroll
  for (int off = 1; off < 64; off <<= 1) s += __shfl_xor(s, off);
  if ((t & 63) == 0) red1[t >> 6] = s;
  __syncthreads();
  float mean = (red1[0] + red1[1] + red1[2] + red1[3]) * (1.f / 1024.f);
  float d0 = x0 - mean, d1 = x1 - mean, d2 = x2 - mean, d3 = x3 - mean;
  float q = d0 * d0 + d1 * d1 + d2 * d2 + d3 * d3;
#pragma unroll
  for (int off = 1; off < 64; off <<= 1) q += __shfl_xor(q, off);
  if ((t & 63) == 0) red2[t >> 6] = q;
  __syncthreads();
  float var = (red2[0] + red2[1] + red2[2] + red2[3]) * (1.f / 1024.f);
  float rs = rsqrtf(var + 1e-5f);
  float4v gv = ((const float4v*)gamma)[t];
  float4v bv = ((const float4v*)beta)[t];
  float4v ov;
  ov.x = d0 * rs * gv.x + bv.x;
  ov.y = d1 * rs * gv.y + bv.y;
  ov.z = d2 * rs * gv.z + bv.z;
  ov.w = d3 * rs * gv.w + bv.w;
  ((float4v*)(out + (size_t)row * 1024))[t] = ov;
}

extern "C" void kernel_launch(void* const* d_in, const int* in_sizes, int n_in,
                              void* d_out, int out_size, void* d_ws, size_t ws_size,
                              hipStream_t stream) {
  (void)in_sizes; (void)n_in; (void)out_size; (void)ws_size;
  const float* h    = (const float*)d_in[0];
  const float* m    = (const float*)d_in[1];
  const float* r    = (const float*)d_in[2];
  const float* Wqkv = (const float*)d_in[4];
  const float* Wr   = (const float*)d_in[5];
  const float* Wo   = (const float*)d_in[6];
  const float* rwb  = (const float*)d_in[7];
  const float* rrb  = (const float*)d_in[8];
  const float* gam  = (const float*)d_in[9];
  const float* bet  = (const float*)d_in[10];
  float* out = (float*)d_out;

  char* ws = (char*)d_ws;
  unsigned short* catB   = (unsigned short*)(ws + 0);          // 16 MB
  unsigned short* WqkvT  = (unsigned short*)(ws + 16777216);   // 6 MB
  unsigned short* WrT    = (unsigned short*)(ws + 23068672);   // 2 MB
  unsigned short* WoT    = (unsigned short*)(ws + 25165824);   // 2 MB
  unsigned short* wheads = (unsigned short*)(ws + 27262976);   // 48 MB (reused as po after repack/vt)
  unsigned short* RkG    = (unsigned short*)(ws + 77594624);   // 4 MB
  unsigned short* VT     = (unsigned short*)(ws + 81788928);   // 16 MB
  float* uk              = (float*)(ws + 98566144);            // 0.5 MB
  float* vr              = (float*)(ws + 99090432);            // 0.125 MB
  unsigned short* vec    = (unsigned short*)(ws + 99221504);   // 8 MB
  float* xbuf            = (float*)(ws + 107610112);           // 16 MB
  unsigned short* rB     = (unsigned short*)(ws + 124387328);  // 4 MB (reused as psumG after GEMM2)
  unsigned short* Kp     = (unsigned short*)(ws + 128581632);  // 16 MB
  unsigned short* Qp     = (unsigned short*)(ws + 145358848);  // 8 MB
  unsigned short* Rkp    = (unsigned short*)(ws + 153747456);  // 4 MB -> ~158 MB total

  float* po    = (float*)(ws + 27262976);   // 50.33 MB over dead wheads
  float* psumG = (float*)(ws + 124387328);  // 0.79 MB over dead rB

  hipLaunchKernelGGL(k_cat_convert, dim3(8192), dim3(256), 0, stream, m, h, catB);
  hipLaunchKernelGGL(k_f32_to_bf16, dim3(2048), dim3(256), 0, stream, r, rB, 524288);
  hipLaunchKernelGGL(k_transpose_bf16, dim3(96, 32), dim3(256), 0, stream, Wqkv, WqkvT, 1024, 3072);
  hipLaunchKernelGGL(k_transpose_bf16, dim3(32, 32), dim3(256), 0, stream, Wr, WrT, 1024, 1024);
  hipLaunchKernelGGL(k_transpose_bf16, dim3(32, 32), dim3(256), 0, stream, Wo, WoT, 1024, 1024);
  // GEMM1 split: KV over all rows (cols 1024..3071), Q only for rows >= 4096
  hipLaunchKernelGGL(k_gemm<0>, dim3(16, 64), dim3(256), 0, stream,
                     catB, WqkvT + (size_t)1024 * 1024, (void*)wheads, 8192, 2048, 1024, 3072, 1024);
  hipLaunchKernelGGL(k_gemm<0>, dim3(8, 32), dim3(256), 0, stream,
                     catB + (size_t)4096 * 1024, WqkvT, (void*)(wheads + (size_t)4096 * 3072),
                     4096, 1024, 1024, 3072, 0);
  hipLaunchKernelGGL(k_gemm<0>, dim3(8, 16), dim3(256), 0, stream, rB, WrT, (void*)RkG, 2048, 1024, 1024, 1024, 0);
  hipLaunchKernelGGL(k_vt, dim3(32, 16, 4), dim3(256), 0, stream, wheads, VT);
  hipLaunchKernelGGL(k_repack, dim3(7168), dim3(256), 0, stream, wheads, RkG, Kp, Qp, Rkp);
  hipLaunchKernelGGL(k_bias_dots, dim3(640), dim3(256), 0, stream, Kp, Rkp, rwb, rrb, uk, vr);
  hipLaunchKernelGGL(k_attn, dim3(3072), dim3(256), 0, stream, Qp, Kp, VT, Rkp, uk, vr, po, psumG);
  hipLaunchKernelGGL(k_ared, dim3(1024), dim3(256), 0, stream, po, psumG, vec);
  hipLaunchKernelGGL(k_gemm<1>, dim3(8, 32), dim3(256), 0, stream, vec, WoT, (void*)xbuf, 4096, 1024, 1024, 1024, 0);
  hipLaunchKernelGGL(k_ln, dim3(4096), dim3(256), 0, stream, xbuf, h, gam, bet, out);
}

// Round 12
// 345.118 us; speedup vs baseline: 1.0742x; 1.0742x over previous
//
#include <hip/hip_runtime.h>
#include <stdint.h>

#define T_LEN 1024
#define MEM_LEN 1024
#define C_LEN 2048
#define B_SZ 4
#define DM_ 1024
#define NH 16
#define HD 64

typedef __attribute__((ext_vector_type(8))) short short8;
typedef __attribute__((ext_vector_type(4))) float f32x4;
typedef __attribute__((ext_vector_type(4))) unsigned short ushort4v;
typedef __attribute__((ext_vector_type(4))) float float4v;

__device__ __forceinline__ unsigned short f2bf(float f) {
  union { float f; unsigned int u; } v; v.f = f;
  unsigned int r = v.u + 0x7fffu + ((v.u >> 16) & 1u);
  return (unsigned short)(r >> 16);
}
__device__ __forceinline__ float bf2f(unsigned short b) {
  union { unsigned int u; float f; } v; v.u = ((unsigned int)b) << 16;
  return v.f;
}
__device__ __forceinline__ f32x4 mfma16(short8 a, short8 b, f32x4 c) {
  return __builtin_amdgcn_mfma_f32_16x16x32_bf16(a, b, c, 0, 0, 0);
}

// ---------------- converts ----------------
__global__ void k_cat_convert(const float* __restrict__ m, const float* __restrict__ h,
                              unsigned short* __restrict__ outB) {
  int idx = blockIdx.x * 256 + threadIdx.x;
  const int MQ = (MEM_LEN * B_SZ * DM_) / 4;
  float4v v;
  if (idx < MQ) v = ((const float4v*)m)[idx];
  else          v = ((const float4v*)h)[idx - MQ];
  ushort4v o;
  o.x = f2bf(v.x); o.y = f2bf(v.y); o.z = f2bf(v.z); o.w = f2bf(v.w);
  ((ushort4v*)outB)[idx] = o;
}

__global__ void k_f32_to_bf16(const float* __restrict__ in, unsigned short* __restrict__ outB, int nq) {
  int idx = blockIdx.x * 256 + threadIdx.x;
  if (idx >= nq) return;
  float4v v = ((const float4v*)in)[idx];
  ushort4v o;
  o.x = f2bf(v.x); o.y = f2bf(v.y); o.z = f2bf(v.z); o.w = f2bf(v.w);
  ((ushort4v*)outB)[idx] = o;
}

// transpose f32 [R][Ccols] -> bf16 [Ccols][R]
__global__ void k_transpose_bf16(const float* __restrict__ in, unsigned short* __restrict__ out,
                                 int R, int Ccols) {
  __shared__ float tile[32][33];
  int c0 = blockIdx.x * 32, r0 = blockIdx.y * 32;
  int tx = threadIdx.x & 31, ty = threadIdx.x >> 5;
#pragma unroll
  for (int p = 0; p < 4; ++p)
    tile[ty + 8 * p][tx] = in[(size_t)(r0 + ty + 8 * p) * Ccols + c0 + tx];
  __syncthreads();
#pragma unroll
  for (int p = 0; p < 4; ++p)
    out[(size_t)(c0 + ty + 8 * p) * R + r0 + tx] = f2bf(tile[tx][ty + 8 * p]);
}

// ---------------- GEMM with direct-layout epilogues, XCD-swizzled grid ----------------
// MODE 1: f32 plain -> out1[row*ldc+col]
// MODE 2: QKV KV-part (A rows = c*4+b). cc=col: cc<1024 -> Kp[b][n][c][d];
//         cc>=1024 -> Vp[b][n][c][d]  (n=(cc&1023)>>6, d=cc&63)
// MODE 3: Q-part (A rows = t*4+b local) -> Qp[b][n][t][d]
// MODE 4: Rk (A rows = c) -> Rkp[n][c][d]
template <int MODE>
__global__ __launch_bounds__(256) void k_gemm(const unsigned short* __restrict__ A,
                                              const unsigned short* __restrict__ BT,
                                              void* __restrict__ out1, void* __restrict__ out2,
                                              int M, int N, int K, int ldc) {
  __shared__ unsigned short As[128 * 64];
  __shared__ unsigned short Bs[128 * 64];
  const int tid = threadIdx.x;
  const int w = tid >> 6, l = tid & 63;
  const int wm = w >> 1, wn = w & 1;
  const int lg = l >> 4, lr = l & 15;
  const int gx = gridDim.x;
  const int pid = blockIdx.y * gx + blockIdx.x;
  const int xcd = pid & 7;
  const int idx = pid >> 3;
  const int cb = idx % gx;
  const int rb = (idx / gx) * 8 + xcd;
  const int m0 = rb * 128, n0 = cb * 128;
  f32x4 acc[4][4] = {};
  const int lrow8 = l >> 3;
  const int scol = (l & 7) * 8;
  const unsigned short* Abase = A + (size_t)m0 * K;
  const unsigned short* Bbase = BT + (size_t)n0 * K;
  for (int kt = 0; kt < K; kt += 64) {
    __syncthreads();
#pragma unroll
    for (int q = 0; q < 4; ++q) {
      int chunk = w * 4 + q;
      int row = chunk * 8 + lrow8;
      __builtin_amdgcn_global_load_lds(
          (const __attribute__((address_space(1))) void*)(Abase + (size_t)row * K + kt + scol),
          (__attribute__((address_space(3))) void*)(As + chunk * 512), 16, 0, 0);
      __builtin_amdgcn_global_load_lds(
          (const __attribute__((address_space(1))) void*)(Bbase + (size_t)row * K + kt + scol),
          (__attribute__((address_space(3))) void*)(Bs + chunk * 512), 16, 0, 0);
    }
    __syncthreads();
#pragma unroll
    for (int ks = 0; ks < 2; ++ks) {
      short8 a[4], bb[4];
#pragma unroll
      for (int mi = 0; mi < 4; ++mi)
        a[mi] = *(const short8*)&As[(wm * 64 + mi * 16 + lr) * 64 + ks * 32 + lg * 8];
#pragma unroll
      for (int ni = 0; ni < 4; ++ni)
        bb[ni] = *(const short8*)&Bs[(wn * 64 + ni * 16 + lr) * 64 + ks * 32 + lg * 8];
#pragma unroll
      for (int mi = 0; mi < 4; ++mi)
#pragma unroll
        for (int ni = 0; ni < 4; ++ni)
          acc[mi][ni] = mfma16(a[mi], bb[ni], acc[mi][ni]);
    }
  }
#pragma unroll
  for (int mi = 0; mi < 4; ++mi)
#pragma unroll
    for (int ni = 0; ni < 4; ++ni)
#pragma unroll
      for (int r = 0; r < 4; ++r) {
        int row = m0 + wm * 64 + mi * 16 + lg * 4 + r;
        int cc = n0 + wn * 64 + ni * 16 + lr;
        float val = acc[mi][ni][r];
        if (MODE == 1) {
          ((float*)out1)[(size_t)row * ldc + cc] = val;
        } else if (MODE == 2) {
          int nn = (cc & 1023) >> 6, d = cc & 63;
          int c = row >> 2, b = row & 3;
          size_t addr = ((size_t)((b * 16 + nn) * 2048 + c)) * 64 + d;
          unsigned short* dst = (cc < 1024) ? (unsigned short*)out1 : (unsigned short*)out2;
          dst[addr] = f2bf(val);
        } else if (MODE == 3) {
          int nn = cc >> 6, d = cc & 63;
          int t = row >> 2, b = row & 3;
          ((unsigned short*)out1)[((size_t)((b * 16 + nn) * 1024 + t)) * 64 + d] = f2bf(val);
        } else {  // MODE 4
          int nn = cc >> 6, d = cc & 63;
          ((unsigned short*)out1)[((size_t)(nn * 2048 + row)) * 64 + d] = f2bf(val);
        }
      }
}

// ---------------- V transpose: Vp[b][n][c][d] -> VT[b][n][d][c] ----------------
__global__ void k_vt(const unsigned short* __restrict__ Vp, unsigned short* __restrict__ VT) {
  __shared__ unsigned short tile[64][72];
  int c0 = blockIdx.x * 64;
  int n = blockIdx.y, b = blockIdx.z;
  int t = threadIdx.x;
  const unsigned short* src = Vp + ((size_t)((b * 16 + n) * 2048 + c0)) * 64;
#pragma unroll
  for (int p = 0; p < 16; ++p) {
    int idx = p * 256 + t;
    int r = idx >> 6, d = idx & 63;
    tile[d][r] = src[(size_t)r * 64 + d];
  }
  __syncthreads();
#pragma unroll
  for (int p = 0; p < 16; ++p) {
    int idx = p * 256 + t;
    int d = idx >> 6, c = idx & 63;
    VT[(size_t)((b * 16 + n) * 64 + d) * 2048 + c0 + c] = tile[d][c];
  }
}

// ---------------- bias dot scalars ----------------
__global__ void k_bias_dots(const unsigned short* __restrict__ Kp,
                            const unsigned short* __restrict__ Rkp,
                            const float* __restrict__ rwb, const float* __restrict__ rrb,
                            float* __restrict__ uk, float* __restrict__ vr) {
  int gid = blockIdx.x * 256 + threadIdx.x;
  if (gid < B_SZ * NH * C_LEN) {
    int bn = gid >> 11;
    int n = bn & 15;
    const unsigned short* kp = Kp + (size_t)gid * 64;
    float s = 0.f;
#pragma unroll
    for (int q = 0; q < 8; ++q) {
      short8 v = *(const short8*)&kp[q * 8];
#pragma unroll
      for (int e = 0; e < 8; ++e)
        s += bf2f((unsigned short)v[e]) * rwb[n * 64 + q * 8 + e];
    }
    uk[gid] = s;
  } else {
    int g2 = gid - B_SZ * NH * C_LEN;
    int n = g2 >> 11;
    const unsigned short* rp = Rkp + (size_t)g2 * 64;
    float s = 0.f;
#pragma unroll
    for (int q = 0; q < 8; ++q) {
      short8 v = *(const short8*)&rp[q * 8];
#pragma unroll
      for (int e = 0; e < 8; ++e)
        s += bf2f((unsigned short)v[e]) * rrb[n * 64 + q * 8 + e];
    }
    vr[g2] = s;
  }
}

// ---------------- split-j flash attention (R10 best: KVBLK=64) ----------------
__device__ __forceinline__ void stage_tile(const unsigned short* __restrict__ Kbase,
                                           const unsigned short* __restrict__ Vbase,
                                           unsigned short* ksBuf, unsigned short* vsBuf,
                                           int j0, int tid) {
#pragma unroll
  for (int q = 0; q < 2; ++q) {
    int chunk = q * 256 + tid;   // 0..511
    int row = chunk >> 3;        // 0..63
    int slot = chunk & 7;
    int ss = slot ^ (row & 7);   // source pre-swizzle (rule #21)
    __builtin_amdgcn_global_load_lds(
        (const __attribute__((address_space(1))) void*)(Kbase + (size_t)(j0 + row) * 64 + ss * 8),
        (__attribute__((address_space(3))) void*)(ksBuf + chunk * 8), 16, 0, 0);
    __builtin_amdgcn_global_load_lds(
        (const __attribute__((address_space(1))) void*)(Vbase + (size_t)row * 2048 + j0 + ss * 8),
        (__attribute__((address_space(3))) void*)(vsBuf + chunk * 8), 16, 0, 0);
  }
}

__global__ __launch_bounds__(256) void k_attn(const unsigned short* __restrict__ Qp,
                                              const unsigned short* __restrict__ Kp,
                                              const unsigned short* __restrict__ VT,
                                              const unsigned short* __restrict__ Rkp,
                                              const float* __restrict__ uk,
                                              const float* __restrict__ vr,
                                              unsigned short* __restrict__ po,
                                              float* __restrict__ psumG) {
  __shared__ __align__(16) unsigned short Ks[2][64 * 64];
  __shared__ __align__(16) unsigned short Vs[2][64 * 64];
  __shared__ unsigned short P[4][16][72];
  const int tid = threadIdx.x;
  const int w = tid >> 6, l = tid & 63;
  const int lg = l >> 4, lr = l & 15;
  // XCD-locality: all 48 (xt,s) blocks of one bn land on one XCD (L%8 const)
  const int L = blockIdx.x;
  const int bnlo = L & 7;
  const int rest = L >> 3;          // 0..383
  const int bnhi = rest / 48;
  const int inner = rest - bnhi * 48;  // 0..47
  const int xt = inner / 3;
  const int s  = inner - xt * 3;
  const int bn = bnhi * 8 + bnlo;
  const int i0 = xt * 64;
  const int n = bn & 15, b = bn >> 4;
  const int wrow = i0 + w * 16;

  const int ntile = xt + 17;
  const int t0 = (s * ntile) / 3;
  const int t1 = ((s + 1) * ntile) / 3;   // chunk length 5..11

  const unsigned short* Kbase = Kp + (size_t)bn * 2048 * 64;
  const unsigned short* Vbase = VT + (size_t)bn * 64 * 2048;
  const unsigned short* Rkbase = Rkp + (size_t)n * 2048 * 64;

  short8 aq0, aq1;
  {
    const unsigned short* qp = Qp + (size_t)(bn * 1024 + wrow + lr) * 64 + lg * 8;
    aq0 = *(const short8*)qp;
    aq1 = *(const short8*)(qp + 32);
  }
  float psum[4];
  f32x4 o[4];
#pragma unroll
  for (int r = 0; r < 4; ++r) psum[r] = 0.f;
#pragma unroll
  for (int df = 0; df < 4; ++df) o[df] = (f32x4){0.f, 0.f, 0.f, 0.f};

  const float* ukp = uk + (size_t)bn * 2048;
  const float* vrp = vr + (size_t)n * 2048;

  // prologue: stage tiles t0, t0+1 (8 loads/thread outstanding)
  stage_tile(Kbase, Vbase, Ks[0], Vs[0], t0 * 64, tid);
  stage_tile(Kbase, Vbase, Ks[1], Vs[1], (t0 + 1) * 64, tid);

  const float EXPC = 0.18033688011112042f;  // 0.125 * log2(e)

  for (int jt = t0; jt < t1; ++jt) {
    const int j0 = jt * 64;
    const int cur = (jt - t0) & 1;
    if (jt + 1 < t1) { asm volatile("s_waitcnt vmcnt(4)" ::: "memory"); }
    else             { asm volatile("s_waitcnt vmcnt(0)" ::: "memory"); }
    __builtin_amdgcn_s_barrier();

    f32x4 sac[4];
#pragma unroll
    for (int jf = 0; jf < 4; ++jf) sac[jf] = (f32x4){0.f, 0.f, 0.f, 0.f};
    // AC = q . k  (from swizzled LDS)
#pragma unroll
    for (int jf = 0; jf < 4; ++jf) {
      int row = jf * 16 + lr;
      int rx = row & 7;
      short8 k0 = *(const short8*)&Ks[cur][row * 64 + ((lg ^ rx) * 8)];
      short8 k1 = *(const short8*)&Ks[cur][row * 64 + (((4 + lg) ^ rx) * 8)];
      sac[jf] = mfma16(aq0, k0, sac[jf]);
      sac[jf] = mfma16(aq1, k1, sac[jf]);
    }
    // BD band fragments, kept in registers
    const int kbw = j0 + 1008 - i0 - w * 16;
    f32x4 gb[5];
#pragma unroll
    for (int jg = 0; jg < 5; ++jg) {
      int rowK = kbw + jg * 16 + lr;
      short8 b0 = {}, b1 = {};
      float vrv = 0.f;
      if (rowK < C_LEN) {
        const unsigned short* rp = Rkbase + (size_t)rowK * 64 + lg * 8;
        b0 = *(const short8*)rp;
        b1 = *(const short8*)(rp + 32);
        vrv = vrp[rowK];
      }
      f32x4 g = (f32x4){0.f, 0.f, 0.f, 0.f};
      g = mfma16(aq0, b0, g);
      g = mfma16(aq1, b1, g);
#pragma unroll
      for (int r = 0; r < 4; ++r) g[r] += vrv;
      gb[jg] = g;
    }
    float ukv[4];
#pragma unroll
    for (int jf = 0; jf < 4; ++jf) ukv[jf] = ukp[j0 + jf * 16 + lr];
    // shuffle-gather the diagonal band; p = exp2(score*C) directly (no max)
    float p[4][4];
#pragma unroll
    for (int r = 0; r < 4; ++r) {
      const int R = lg * 4 + r;
      const int delta = lr + 15 - R;
      const int src = (l & 48) | (delta & 15);
      float v0 = __shfl(gb[0][r], src);
      float v1 = __shfl(gb[1][r], src);
      float v2 = __shfl(gb[2][r], src);
      float v3 = __shfl(gb[3][r], src);
      float v4 = __shfl(gb[4][r], src);
      const bool hi = delta >= 16;
      float bd0 = hi ? v1 : v0;
      float bd1 = hi ? v2 : v1;
      float bd2 = hi ? v3 : v2;
      float bd3 = hi ? v4 : v3;
      const int jlim = i0 + w * 16 + R + MEM_LEN;
      int j = j0 + lr;
      p[0][r] = (j > jlim) ? 0.f : exp2f((sac[0][r] + bd0 + ukv[0]) * EXPC);
      j += 16;
      p[1][r] = (j > jlim) ? 0.f : exp2f((sac[1][r] + bd1 + ukv[1]) * EXPC);
      j += 16;
      p[2][r] = (j > jlim) ? 0.f : exp2f((sac[2][r] + bd2 + ukv[2]) * EXPC);
      j += 16;
      p[3][r] = (j > jlim) ? 0.f : exp2f((sac[3][r] + bd3 + ukv[3]) * EXPC);
    }
#pragma unroll
    for (int jf = 0; jf < 4; ++jf)
#pragma unroll
      for (int r = 0; r < 4; ++r) psum[r] += p[jf][r];
#pragma unroll
    for (int jf = 0; jf < 4; ++jf)
#pragma unroll
      for (int r = 0; r < 4; ++r)
        P[w][lg * 4 + r][jf * 16 + lr] = f2bf(p[jf][r]);
    // PV (V from swizzled LDS), no rescale
#pragma unroll
    for (int ks = 0; ks < 2; ++ks) {
      short8 ap = *(const short8*)&P[w][lr][ks * 32 + lg * 8];
#pragma unroll
      for (int df = 0; df < 4; ++df) {
        int row = df * 16 + lr;
        int rx = row & 7;
        short8 vv = *(const short8*)&Vs[cur][row * 64 + (((ks * 4 + lg) ^ rx) * 8)];
        o[df] = mfma16(ap, vv, o[df]);
      }
    }
    __builtin_amdgcn_s_barrier();
    if (jt + 2 < t1)
      stage_tile(Kbase, Vbase, Ks[cur], Vs[cur], (jt + 2) * 64, tid);
  }
  // write partials (o as bf16)
  const int pbase = (bn * 16 + xt) * 3 + s;
  unsigned short* poB = po + (size_t)pbase * 4096;
#pragma unroll
  for (int r = 0; r < 4; ++r) {
    float v = psum[r];
    v += __shfl_xor(v, 1);
    v += __shfl_xor(v, 2);
    v += __shfl_xor(v, 4);
    v += __shfl_xor(v, 8);
    if (lr == 0) psumG[pbase * 64 + w * 16 + lg * 4 + r] = v;
  }
#pragma unroll
  for (int df = 0; df < 4; ++df)
#pragma unroll
    for (int r = 0; r < 4; ++r)
      poB[(w * 16 + lg * 4 + r) * 64 + df * 16 + lr] = f2bf(o[df][r]);
}

// combine split partials, normalize, emit bf16 vec[t][b][n*64+d]
__global__ __launch_bounds__(256) void k_ared(const unsigned short* __restrict__ po,
                                              const float* __restrict__ psumG,
                                              unsigned short* __restrict__ vec) {
  const int idx = blockIdx.x;      // bn*16 + xt
  const int tid = threadIdx.x;
  const int bn = idx >> 4, xt = idx & 15;
  const int b = bn >> 4, n = bn & 15;
  __shared__ float rs[64];
  if (tid < 64) {
    const float* q = psumG + idx * 192;
    rs[tid] = q[tid] + q[tid + 64] + q[tid + 128];
  }
  __syncthreads();
  const ushort4v* p0 = (const ushort4v*)(po + (size_t)(idx * 3 + 0) * 4096);
  const ushort4v* p1 = (const ushort4v*)(po + (size_t)(idx * 3 + 1) * 4096);
  const ushort4v* p2 = (const ushort4v*)(po + (size_t)(idx * 3 + 2) * 4096);
#pragma unroll
  for (int k = 0; k < 4; ++k) {
    int e = tid + k * 256;          // ushort4 index 0..1023
    int row = e >> 4, d4 = e & 15;
    ushort4v a = p0[e], bb = p1[e], c = p2[e];
    float inv = 1.f / rs[row];
    int t = xt * 64 + row;
    ushort4v ov;
    ov.x = f2bf((bf2f(a.x) + bf2f(bb.x) + bf2f(c.x)) * inv);
    ov.y = f2bf((bf2f(a.y) + bf2f(bb.y) + bf2f(c.y)) * inv);
    ov.z = f2bf((bf2f(a.z) + bf2f(bb.z) + bf2f(c.z)) * inv);
    ov.w = f2bf((bf2f(a.w) + bf2f(bb.w) + bf2f(c.w)) * inv);
    *(ushort4v*)&vec[(size_t)(t * 4 + b) * 1024 + n * 64 + d4 * 4] = ov;
  }
}

// ---------------- residual + layernorm ----------------
__global__ __launch_bounds__(256) void k_ln(const float* __restrict__ xg, const float* __restrict__ h,
                                            const float* __restrict__ gamma, const float* __restrict__ beta,
                                            float* __restrict__ out) {
  const int row = blockIdx.x;
  const int t = threadIdx.x;
  __shared__ float red1[4], red2[4];
  float4v xv = ((const float4v*)(xg + (size_t)row * 1024))[t];
  float4v hv = ((const float4v*)(h + (size_t)row * 1024))[t];
  float x0 = xv.x + hv.x, x1 = xv.y + hv.y, x2 = xv.z + hv.z, x3 = xv.w + hv.w;
  float s = x0 + x1 + x2 + x3;
#pragma unroll
  for (int off = 1; off < 64; off <<= 1) s += __shfl_xor(s, off);
  if ((t & 63) == 0) red1[t >> 6] = s;
  __syncthreads();
  float mean = (red1[0] + red1[1] + red1[2] + red1[3]) * (1.f / 1024.f);
  float d0 = x0 - mean, d1 = x1 - mean, d2 = x2 - mean, d3 = x3 - mean;
  float q = d0 * d0 + d1 * d1 + d2 * d2 + d3 * d3;
#pragma unroll
  for (int off = 1; off < 64; off <<= 1) q += __shfl_xor(q, off);
  if ((t & 63) == 0) red2[t >> 6] = q;
  __syncthreads();
  float var = (red2[0] + red2[1] + red2[2] + red2[3]) * (1.f / 1024.f);
  float rs = rsqrtf(var + 1e-5f);
  float4v gv = ((const float4v*)gamma)[t];
  float4v bv = ((const float4v*)beta)[t];
  float4v ov;
  ov.x = d0 * rs * gv.x + bv.x;
  ov.y = d1 * rs * gv.y + bv.y;
  ov.z = d2 * rs * gv.z + bv.z;
  ov.w = d3 * rs * gv.w + bv.w;
  ((float4v*)(out + (size_t)row * 1024))[t] = ov;
}

extern "C" void kernel_launch(void* const* d_in, const int* in_sizes, int n_in,
                              void* d_out, int out_size, void* d_ws, size_t ws_size,
                              hipStream_t stream) {
  (void)in_sizes; (void)n_in; (void)out_size; (void)ws_size;
  const float* h    = (const float*)d_in[0];
  const float* m    = (const float*)d_in[1];
  const float* r    = (const float*)d_in[2];
  const float* Wqkv = (const float*)d_in[4];
  const float* Wr   = (const float*)d_in[5];
  const float* Wo   = (const float*)d_in[6];
  const float* rwb  = (const float*)d_in[7];
  const float* rrb  = (const float*)d_in[8];
  const float* gam  = (const float*)d_in[9];
  const float* bet  = (const float*)d_in[10];
  float* out = (float*)d_out;

  char* ws = (char*)d_ws;
  unsigned short* catB   = (unsigned short*)(ws + 0);          // 16 MB
  unsigned short* WqkvT  = (unsigned short*)(ws + 16777216);   // 6 MB
  unsigned short* WrT    = (unsigned short*)(ws + 23068672);   // 2 MB
  unsigned short* WoT    = (unsigned short*)(ws + 25165824);   // 2 MB
  unsigned short* Vp     = (unsigned short*)(ws + 27262976);   // 16 MB (old wheads region)
  unsigned short* po     = (unsigned short*)(ws + 44040192);   // 24 MB bf16 partials (ends 69206016)
  unsigned short* VT     = (unsigned short*)(ws + 81788928);   // 16 MB
  float* uk              = (float*)(ws + 98566144);            // 0.5 MB
  float* vr              = (float*)(ws + 99090432);            // 0.125 MB
  unsigned short* vec    = (unsigned short*)(ws + 99221504);   // 8 MB
  float* xbuf            = (float*)(ws + 107610112);           // 16 MB
  unsigned short* rB     = (unsigned short*)(ws + 124387328);  // 4 MB (reused as psumG after GEMM-Rk)
  unsigned short* Kp     = (unsigned short*)(ws + 128581632);  // 16 MB
  unsigned short* Qp     = (unsigned short*)(ws + 145358848);  // 8 MB
  unsigned short* Rkp    = (unsigned short*)(ws + 153747456);  // 4 MB -> ~158 MB total
  float* psumG = (float*)(ws + 124387328);                     // over dead rB

  hipLaunchKernelGGL(k_cat_convert, dim3(8192), dim3(256), 0, stream, m, h, catB);
  hipLaunchKernelGGL(k_f32_to_bf16, dim3(2048), dim3(256), 0, stream, r, rB, 524288);
  hipLaunchKernelGGL(k_transpose_bf16, dim3(96, 32), dim3(256), 0, stream, Wqkv, WqkvT, 1024, 3072);
  hipLaunchKernelGGL(k_transpose_bf16, dim3(32, 32), dim3(256), 0, stream, Wr, WrT, 1024, 1024);
  hipLaunchKernelGGL(k_transpose_bf16, dim3(32, 32), dim3(256), 0, stream, Wo, WoT, 1024, 1024);
  // QKV GEMMs with direct-layout epilogues (k_repack deleted)
  hipLaunchKernelGGL(k_gemm<2>, dim3(16, 64), dim3(256), 0, stream,
                     catB, WqkvT + (size_t)1024 * 1024, (void*)Kp, (void*)Vp, 8192, 2048, 1024, 0);
  hipLaunchKernelGGL(k_gemm<3>, dim3(8, 32), dim3(256), 0, stream,
                     catB + (size_t)4096 * 1024, WqkvT, (void*)Qp, nullptr, 4096, 1024, 1024, 0);
  hipLaunchKernelGGL(k_gemm<4>, dim3(8, 16), dim3(256), 0, stream,
                     rB, WrT, (void*)Rkp, nullptr, 2048, 1024, 1024, 0);
  hipLaunchKernelGGL(k_vt, dim3(32, 16, 4), dim3(256), 0, stream, Vp, VT);
  hipLaunchKernelGGL(k_bias_dots, dim3(640), dim3(256), 0, stream, Kp, Rkp, rwb, rrb, uk, vr);
  hipLaunchKernelGGL(k_attn, dim3(3072), dim3(256), 0, stream, Qp, Kp, VT, Rkp, uk, vr, po, psumG);
  hipLaunchKernelGGL(k_ared, dim3(1024), dim3(256), 0, stream, po, psumG, vec);
  hipLaunchKernelGGL(k_gemm<1>, dim3(8, 32), dim3(256), 0, stream,
                     vec, WoT, (void*)xbuf, nullptr, 4096, 1024, 1024, 1024);
  hipLaunchKernelGGL(k_ln, dim3(4096), dim3(256), 0, stream, xbuf, h, gam, bet, out);
}